// Round 5
// baseline (300.208 us; speedup 1.0000x reference)
//
#include <hip/hip_runtime.h>
#include <stdint.h>

#define BS 8
#define LQ 256
#define HH 192
#define WW 192
#define HW (HH*WW)     /* 36864 */
#define KK 16
#define QCAP 320       /* per (wave,query) queue; drain threshold 64, max site add 256 */
#define PAD 1e-4f      /* filter safety margin (fma-vs-exact error < 5e-6) */

typedef unsigned long long u64;

// ---------- helpers ----------

__device__ __forceinline__ uint32_t fkey(float f) {
    uint32_t u = __float_as_uint(f);
    uint32_t mask = (uint32_t)((int32_t)u >> 31) | 0x80000000u;
    return u ^ mask;
}
__device__ __forceinline__ float inv_fkey(uint32_t v) {
    uint32_t u = (v & 0x80000000u) ? (v ^ 0x80000000u) : ~v;
    return __uint_as_float(u);
}

__device__ __forceinline__ u64 umin64(u64 a, u64 b) { return a < b ? a : b; }

__device__ __forceinline__ u64 wave_min_u64(u64 v) {
    #pragma unroll
    for (int off = 32; off >= 1; off >>= 1) {
        uint32_t lo = (uint32_t)v, hi = (uint32_t)(v >> 32);
        lo = __shfl_xor(lo, off, 64);
        hi = __shfl_xor(hi, off, 64);
        u64 o = ((u64)hi << 32) | lo;
        v = umin64(v, o);
    }
    return v;
}

__device__ __forceinline__ void insert64(u64 (&kept)[KK], u64 key) {
    #pragma unroll
    for (int j = KK - 1; j >= 1; --j) {
        u64 a = kept[j - 1];
        u64 mn = umin64(kept[j], key);
        kept[j] = (key < a) ? a : mn;
    }
    kept[0] = umin64(kept[0], key);
}

// ascending bitonic sort of 16 u64 in registers
__device__ __forceinline__ void bitonic16(u64 (&w)[KK]) {
    #pragma unroll
    for (int k = 2; k <= 16; k <<= 1) {
        #pragma unroll
        for (int j = k >> 1; j > 0; j >>= 1) {
            #pragma unroll
            for (int i = 0; i < 16; ++i) {
                int p = i ^ j;
                if (p > i) {
                    bool up = ((i & k) == 0);
                    u64 a = w[i], c = w[p];
                    bool sw = (a > c) == up;
                    w[i] = sw ? c : a;
                    w[p] = sw ? a : c;
                }
            }
        }
    }
}

// binary search in monotone key space: smallest hi with wave-cnt(kept<=hi) >= 16 (bracketed)
__device__ __forceinline__ uint32_t refine_tau(const u64 (&kept)[KK], uint32_t hi, int iters) {
    uint32_t khi[KK];
    #pragma unroll
    for (int j = 0; j < KK; ++j) khi[j] = (uint32_t)(kept[j] >> 32);
    uint32_t lo = 0x00800000u;             // fkey(-FLT_MAX)
    #pragma unroll 1
    for (int t = 0; t < iters; ++t) {
        uint32_t mid = lo + ((hi - lo) >> 1);
        int c = 0;
        #pragma unroll
        for (int j = 0; j < KK; ++j) c += (khi[j] <= mid) ? 1 : 0;
        #pragma unroll
        for (int off = 32; off >= 1; off >>= 1) c += __shfl_xor(c, off, 64);
        if (c >= KK) hi = mid; else lo = mid + 1;
    }
    return hi;
}

__device__ __forceinline__ float exact_rsq(float a, float b, float c) {
    return __fadd_rn(__fadd_rn(__fmul_rn(a, a), __fmul_rn(b, b)), __fmul_rn(c, c));
}
__device__ __forceinline__ float exact_sim(float c0, float c1, float c2, float rsq, float4 pq) {
    float cr = __fadd_rn(__fadd_rn(__fmul_rn(c0, pq.x), __fmul_rn(c1, pq.y)), __fmul_rn(c2, pq.z));
    return __fadd_rn(__fsub_rn(rsq, __fmul_rn(2.0f, cr)), pq.w);
}

// stage compaction: count kept<=tk, exclusive base via wave scan; write prefix to cb if M<=64
__device__ __forceinline__ int stage_compact(const u64 (&kept)[KK], uint32_t tk, u64* cb, int lane) {
    int c = 0;
    #pragma unroll
    for (int j = 0; j < KK; ++j) c += ((uint32_t)(kept[j] >> 32) <= tk) ? 1 : 0;
    int pref = c;
    #pragma unroll
    for (int i = 1; i < 64; i <<= 1) {
        int t = __shfl_up(pref, i, 64);
        if (lane >= i) pref += t;
    }
    int M = __shfl(pref, 63, 64);
    int base = pref - c;
    if (M <= 64) {
        #pragma unroll
        for (int j = 0; j < KK; ++j)
            if (j < c) cb[base + j] = kept[j];     // sorted => prefix are the <=tk ones
    }
    return M;
}

// write this wave's exact top-16 (ascending) into mrow[0..15]
__device__ __forceinline__ void select16(u64 (&kept)[KK], int M, const u64* cb, u64* mrow, int lane) {
    if (M <= 64) {
        u64 my = (lane < M) ? cb[lane] : ~0ull;
        int rank = 0;
        #pragma unroll 1
        for (int m = 0; m < M; ++m) rank += (cb[m] < my) ? 1 : 0;
        if (lane < M && rank < KK) mrow[rank] = my;
    } else {
        #pragma unroll 1
        for (int r = 0; r < KK; ++r) {
            u64 m = wave_min_u64(kept[0]);
            if (kept[0] == m) {
                #pragma unroll
                for (int j = 0; j < KK - 1; ++j) kept[j] = kept[j + 1];
                kept[KK - 1] = ~0ull;
            }
            if (lane == 0) mrow[r] = m;
        }
    }
}

// ---------- kernel 1: fused topk — block = 2 queries of image b, 4 waves split image ----------
__global__ __launch_bounds__(256, 4) void topk_kernel(const float* __restrict__ pred,
                                                      const float* __restrict__ ref,
                                                      uint32_t* __restrict__ topkbuf) {
    __shared__ u64 qbuf[4][2][QCAP];    // 20 KB
    __shared__ u64 cbufs[4][2][64];     // 4 KB
    __shared__ u64 mbuf[2][64];         // 1 KB
    __shared__ float4 spool[2];

    int lane = threadIdx.x & 63;
    int wid  = threadIdx.x >> 6;
    int b  = blockIdx.x & 7;            // XCD swizzle: same image -> same XCD
    int qp = blockIdx.x >> 3;           // 0..127

    // ---- pooled for the block's 2 queries (threads 0,1) ----
    if (threadIdx.x < 2) {
        int l = qp * 2 + threadIdx.x;
        int i = l * BS + b;             // scrambled flat grid row
        int b2 = i >> 8, l2 = i & 255;
        const float* pr = pred + ((b2 * 256 + l2) * 8);
        float x = pr[0], y = pr[1];
        float fx = rintf(__fsub_rn(__fmul_rn(x, 192.0f), 0.5f));
        float fy = rintf(__fsub_rn(__fmul_rn(y, 192.0f), 0.5f));
        int ix = (int)fx, iy = (int)fy;
        int inb = (ix >= 0 && ix < WW && iy >= 0 && iy < HH) ? 1 : 0;
        int ixc = min(max(ix, 0), WW - 1);
        int iyc = min(max(iy, 0), HH - 1);
        float m = (float)inb;
        const float* img = ref + b * 3 * HW + iyc * WW + ixc;
        float p0 = __fmul_rn(img[0], m);
        float p1 = __fmul_rn(img[HW], m);
        float p2 = __fmul_rn(img[2 * HW], m);
        float psq = __fadd_rn(__fadd_rn(__fmul_rn(p0, p0), __fmul_rn(p1, p1)), __fmul_rn(p2, p2));
        spool[threadIdx.x] = make_float4(p0, p1, p2, psq);
    }
    __syncthreads();
    float4 pq0 = spool[0];
    float4 pq1 = spool[1];

    const float4* p0g = (const float4*)(ref + (size_t)b * 3 * HW);   // +9216/+18432 for c1/c2
    int wq4 = wid * 2304;               // this wave's quarter, float4 units
    u64* qw0 = qbuf[wid][0];
    u64* qw1 = qbuf[wid][1];

    // ---- warm-up: quarter's first 4 sites, exact sims, bitonic into kept ----
    u64 w0[KK], w1[KK];
    #pragma unroll
    for (int it = 0; it < 4; ++it) {
        int v = wq4 + it * 64 + lane;
        float4 a0 = p0g[v], a1 = p0g[v + 9216], a2 = p0g[v + 18432];
        int base = v * 4;
        #define WARM(comp, e)                                                      \
        {                                                                          \
            float rs = exact_rsq(a0.comp, a1.comp, a2.comp);                       \
            float s0 = exact_sim(a0.comp, a1.comp, a2.comp, rs, pq0);              \
            float s1 = exact_sim(a0.comp, a1.comp, a2.comp, rs, pq1);              \
            w0[it * 4 + e] = ((u64)fkey(s0) << 32) | (uint32_t)(base + e);         \
            w1[it * 4 + e] = ((u64)fkey(s1) << 32) | (uint32_t)(base + e);         \
        }
        WARM(x, 0) WARM(y, 1) WARM(z, 2) WARM(w, 3)
        #undef WARM
    }
    bitonic16(w0);
    bitonic16(w1);
    u64 (&kept0)[KK] = w0;
    u64 (&kept1)[KK] = w1;

    uint32_t tk0 = refine_tau(kept0, 0xFF7FFFFFu, 12);
    uint32_t tk1 = refine_tau(kept1, 0xFF7FFFFFu, 12);
    float h0 = __fmul_rn(__fsub_rn(pq0.w, __fadd_rn(inv_fkey(tk0), PAD)), 0.5f);
    float h1 = __fmul_rn(__fsub_rn(pq1.w, __fadd_rn(inv_fkey(tk1), PAD)), 0.5f);

    // ---- main scan: sites 4..35 of the quarter, 1-site prefetch ----
    uint32_t scnt0 = 0, scnt1 = 0;
    int vp = wq4 + 4 * 64 + lane;
    float4 n0 = p0g[vp], n1 = p0g[vp + 9216], n2 = p0g[vp + 18432];

    #pragma unroll 1
    for (int it = 4; it < 36; ++it) {
        float4 a0 = n0, a1 = n1, a2 = n2;
        int itn = (it < 35) ? it + 1 : 35;
        int vn = wq4 + itn * 64 + lane;
        n0 = p0g[vn]; n1 = p0g[vn + 9216]; n2 = p0g[vn + 18432];

        int base = (wq4 + it * 64 + lane) * 4;
        // fast filter: pass <=> cross_fma >= fma(rsq, 0.5, h_q)  (pad-safe)
        #define FILT(comp, rs, f0, f1, g0, g1)                                     \
            float rs = exact_rsq(a0.comp, a1.comp, a2.comp);                       \
            float f0 = fmaf(a2.comp, pq0.z, fmaf(a1.comp, pq0.y, a0.comp * pq0.x));\
            float f1 = fmaf(a2.comp, pq1.z, fmaf(a1.comp, pq1.y, a0.comp * pq1.x));\
            bool g0 = f0 >= fmaf(rs, 0.5f, h0);                                    \
            bool g1 = f1 >= fmaf(rs, 0.5f, h1);
        FILT(x, rs0, c00, c10, p00, p10)
        FILT(y, rs1, c01, c11, p01, p11)
        FILT(z, rs2, c02, c12, p02, p12)
        FILT(w, rs3, c03, c13, p03, p13)
        #undef FILT

        bool anyl = p00 | p01 | p02 | p03 | p10 | p11 | p12 | p13;
        if (__ballot(anyl)) {
            #define PUSHQ(pp, e, rsv, PQ, QW, SC)                                              \
            {                                                                                  \
                u64 pm = __ballot(pp);                                                         \
                if (pm) {                                                                      \
                    if (pp) {                                                                  \
                        float sx = exact_sim(a0.e, a1.e, a2.e, rsv, PQ);                       \
                        uint32_t rank = __builtin_amdgcn_mbcnt_hi((uint32_t)(pm >> 32),        \
                                         __builtin_amdgcn_mbcnt_lo((uint32_t)pm, 0));          \
                        QW[SC + rank] = ((u64)fkey(sx) << 32) | (uint32_t)(base + eidx);       \
                    }                                                                          \
                    SC += (uint32_t)__popcll(pm);                                              \
                }                                                                              \
            }
            { const int eidx = 0; PUSHQ(p00, x, rs0, pq0, qw0, scnt0) }
            { const int eidx = 1; PUSHQ(p01, y, rs1, pq0, qw0, scnt0) }
            { const int eidx = 2; PUSHQ(p02, z, rs2, pq0, qw0, scnt0) }
            { const int eidx = 3; PUSHQ(p03, w, rs3, pq0, qw0, scnt0) }
            { const int eidx = 0; PUSHQ(p10, x, rs0, pq1, qw1, scnt1) }
            { const int eidx = 1; PUSHQ(p11, y, rs1, pq1, qw1, scnt1) }
            { const int eidx = 2; PUSHQ(p12, z, rs2, pq1, qw1, scnt1) }
            { const int eidx = 3; PUSHQ(p13, w, rs3, pq1, qw1, scnt1) }
            #undef PUSHQ

            if (scnt0 >= 64u) {
                for (uint32_t e = lane; e < scnt0; e += 64) insert64(kept0, qw0[e]);
                scnt0 = 0;
                tk0 = refine_tau(kept0, tk0, 8);
                h0 = __fmul_rn(__fsub_rn(pq0.w, __fadd_rn(inv_fkey(tk0), PAD)), 0.5f);
            }
            if (scnt1 >= 64u) {
                for (uint32_t e = lane; e < scnt1; e += 64) insert64(kept1, qw1[e]);
                scnt1 = 0;
                tk1 = refine_tau(kept1, tk1, 8);
                h1 = __fmul_rn(__fsub_rn(pq1.w, __fadd_rn(inv_fkey(tk1), PAD)), 0.5f);
            }
        }
    }
    for (uint32_t e = lane; e < scnt0; e += 64) insert64(kept0, qw0[e]);
    for (uint32_t e = lane; e < scnt1; e += 64) insert64(kept1, qw1[e]);

    // ---- per-wave top-16 extraction, then 4-wave merge per query ----
    int M0 = stage_compact(kept0, tk0, cbufs[wid][0], lane);
    int M1 = stage_compact(kept1, tk1, cbufs[wid][1], lane);
    __syncthreads();
    select16(kept0, M0, cbufs[wid][0], &mbuf[0][wid * KK], lane);
    select16(kept1, M1, cbufs[wid][1], &mbuf[1][wid * KK], lane);
    __syncthreads();

    if (wid < 2) {
        int q = wid;
        u64 v = mbuf[q][lane];          // 64 candidates = 4 waves x 16, all distinct
        int rank = 0;
        #pragma unroll 1
        for (int m = 0; m < 64; ++m) {
            uint32_t lo = __shfl((uint32_t)v, m, 64);
            uint32_t hi = __shfl((uint32_t)(v >> 32), m, 64);
            u64 o = ((u64)hi << 32) | lo;
            rank += (o < v) ? 1 : 0;
        }
        if (rank < KK) {
            int l = qp * 2 + q;
            topkbuf[((size_t)(b * 256 + l)) * KK + rank] = (uint32_t)v;
        }
    }
}

// ---------- kernel 2: argmin over rolled targets + loss + mean (single block) ----------
__global__ __launch_bounds__(256) void loss_kernel(const float* __restrict__ pred,
                                                   const uint32_t* __restrict__ topkbuf,
                                                   float* __restrict__ out) {
    double acc = 0.0;
    for (int b = 0; b < BS; ++b) {
        int t = b * 256 + threadIdx.x;
        int l = threadIdx.x;
        float px = pred[(size_t)t * 8 + 0];
        float py = pred[(size_t)t * 8 + 1];
        int lp = (l + LQ - 1) & (LQ - 1);      // roll(shift=1)
        const uint32_t* id = topkbuf + ((size_t)(b * 256 + lp)) * KK;
        float best_d = __int_as_float(0x7f800000);
        float bx = 0.0f, by = 0.0f;
        #pragma unroll
        for (int k = 0; k < KK; ++k) {
            uint32_t idx = id[k];
            float tx = (float)(idx % WW) / 192.0f;
            float ty = (float)(idx / WW) / 192.0f;
            float dx = __fsub_rn(px, tx);
            float dy = __fsub_rn(py, ty);
            float d = __fadd_rn(__fmul_rn(dx, dx), __fmul_rn(dy, dy));
            if (d < best_d) { best_d = d; bx = tx; by = ty; }
        }
        if (l >= 1) {
            float ex = __fsub_rn(px, bx);
            float ey = __fsub_rn(py, by);
            acc += (double)__fadd_rn(__fmul_rn(ex, ex), __fmul_rn(ey, ey));
        }
    }
    __shared__ double sred[256];
    sred[threadIdx.x] = acc;
    __syncthreads();
    for (int s = 128; s > 0; s >>= 1) {
        if (threadIdx.x < s) sred[threadIdx.x] += sred[threadIdx.x + s];
        __syncthreads();
    }
    if (threadIdx.x == 0) out[0] = (float)(sred[0] / 2040.0);
}

// ---------- launch ----------
extern "C" void kernel_launch(void* const* d_in, const int* in_sizes, int n_in,
                              void* d_out, int out_size, void* d_ws, size_t ws_size,
                              hipStream_t stream) {
    const float* pred = (const float*)d_in[0];   // (8,256,8) f32
    const float* ref  = (const float*)d_in[1];   // (8,3,192,192) f32
    float* out = (float*)d_out;

    uint32_t* topkbuf = (uint32_t*)d_ws;         // 2048*16*4 = 128 KB

    topk_kernel<<<1024, 256, 0, stream>>>(pred, ref, topkbuf);
    loss_kernel<<<1, 256, 0, stream>>>(pred, topkbuf, out);
}

// Round 6
// 145.227 us; speedup vs baseline: 2.0672x; 2.0672x over previous
//
#include <hip/hip_runtime.h>
#include <stdint.h>

#define BS 8
#define LQ 256
#define HH 192
#define WW 192
#define HW (HH*WW)     /* 36864 */
#define KK 16
#define QCAP 320       /* drain at >=64; max site add 256 -> 63+256=319 < 320 */
#define PAD 1e-4f      /* filter safety margin; fma-vs-exact error ~1e-6 */

typedef unsigned long long u64;

// ---------- helpers ----------

__device__ __forceinline__ uint32_t fkey(float f) {
    uint32_t u = __float_as_uint(f);
    uint32_t mask = (uint32_t)((int32_t)u >> 31) | 0x80000000u;
    return u ^ mask;
}
__device__ __forceinline__ float inv_fkey(uint32_t v) {
    uint32_t u = (v & 0x80000000u) ? (v ^ 0x80000000u) : ~v;
    return __uint_as_float(u);
}

__device__ __forceinline__ u64 umin64(u64 a, u64 b) { return a < b ? a : b; }

__device__ __forceinline__ u64 wave_min_u64(u64 v) {
    #pragma unroll
    for (int off = 32; off >= 1; off >>= 1) {
        uint32_t lo = (uint32_t)v, hi = (uint32_t)(v >> 32);
        lo = __shfl_xor(lo, off, 64);
        hi = __shfl_xor(hi, off, 64);
        u64 o = ((u64)hi << 32) | lo;
        v = umin64(v, o);
    }
    return v;
}

__device__ __forceinline__ void insert64(u64 (&kept)[KK], u64 key) {
    #pragma unroll
    for (int j = KK - 1; j >= 1; --j) {
        u64 a = kept[j - 1];
        u64 mn = umin64(kept[j], key);
        kept[j] = (key < a) ? a : mn;
    }
    kept[0] = umin64(kept[0], key);
}

__device__ __forceinline__ void bitonic16(u64 (&w)[KK]) {
    #pragma unroll
    for (int k = 2; k <= 16; k <<= 1) {
        #pragma unroll
        for (int j = k >> 1; j > 0; j >>= 1) {
            #pragma unroll
            for (int i = 0; i < 16; ++i) {
                int p = i ^ j;
                if (p > i) {
                    bool up = ((i & k) == 0);
                    u64 a = w[i], c = w[p];
                    bool sw = (a > c) == up;
                    w[i] = sw ? c : a;
                    w[p] = sw ? a : c;
                }
            }
        }
    }
}

// binary search: tau key with wave-cnt(kept<=tau) >= 16 (hi stays a sound bound)
__device__ __forceinline__ uint32_t refine_tau(const u64 (&kept)[KK], uint32_t hi, int iters) {
    uint32_t khi[KK];
    #pragma unroll
    for (int j = 0; j < KK; ++j) khi[j] = (uint32_t)(kept[j] >> 32);
    uint32_t lo = 0x00800000u;             // fkey(-FLT_MAX)
    #pragma unroll 1
    for (int t = 0; t < iters; ++t) {
        uint32_t mid = lo + ((hi - lo) >> 1);
        int c = 0;
        #pragma unroll
        for (int j = 0; j < KK; ++j) c += (khi[j] <= mid) ? 1 : 0;
        #pragma unroll
        for (int off = 32; off >= 1; off >>= 1) c += __shfl_xor(c, off, 64);
        if (c >= KK) hi = mid; else lo = mid + 1;
    }
    return hi;
}

__device__ __forceinline__ float exact_rsq(float a, float b, float c) {
    return __fadd_rn(__fadd_rn(__fmul_rn(a, a), __fmul_rn(b, b)), __fmul_rn(c, c));
}
__device__ __forceinline__ float exact_sim(float c0, float c1, float c2, float rsq, float4 pq) {
    float cr = __fadd_rn(__fadd_rn(__fmul_rn(c0, pq.x), __fmul_rn(c1, pq.y)), __fmul_rn(c2, pq.z));
    return __fadd_rn(__fsub_rn(rsq, __fmul_rn(2.0f, cr)), pq.w);
}

__device__ __forceinline__ int stage_compact(const u64 (&kept)[KK], uint32_t tk, u64* cb, int lane) {
    int c = 0;
    #pragma unroll
    for (int j = 0; j < KK; ++j) c += ((uint32_t)(kept[j] >> 32) <= tk) ? 1 : 0;
    int pref = c;
    #pragma unroll
    for (int i = 1; i < 64; i <<= 1) {
        int t = __shfl_up(pref, i, 64);
        if (lane >= i) pref += t;
    }
    int M = __shfl(pref, 63, 64);
    int base = pref - c;
    if (M <= 64) {
        #pragma unroll
        for (int j = 0; j < KK; ++j)
            if (j < c) cb[base + j] = kept[j];
    }
    return M;
}

__device__ __forceinline__ void select16(u64 (&kept)[KK], int M, const u64* cb, u64* mrow, int lane) {
    if (M <= 64) {
        u64 my = (lane < M) ? cb[lane] : ~0ull;
        int rank = 0;
        #pragma unroll 1
        for (int m = 0; m < M; ++m) rank += (cb[m] < my) ? 1 : 0;
        if (lane < M && rank < KK) mrow[rank] = my;
    } else {   // fallback, exact
        #pragma unroll 1
        for (int r = 0; r < KK; ++r) {
            u64 m = wave_min_u64(kept[0]);
            if (kept[0] == m) {
                #pragma unroll
                for (int j = 0; j < KK - 1; ++j) kept[j] = kept[j + 1];
                kept[KK - 1] = ~0ull;
            }
            if (lane == 0) mrow[r] = m;
        }
    }
}

// ---------- kernel 1: block = one query (b,l); 4 waves split image; emits loss term ----------
__global__ __launch_bounds__(256) void topk_kernel(const float* __restrict__ pred,
                                                   const float* __restrict__ ref,
                                                   float* __restrict__ partial) {
    __shared__ u64 qbuf[4][QCAP];    // 10.0 KB
    __shared__ u64 cbufs[4][64];     // 2 KB
    __shared__ u64 mbuf[64];         // 0.5 KB
    __shared__ float4 spool;

    int lane = threadIdx.x & 63;
    int wid  = threadIdx.x >> 6;
    int b  = blockIdx.x & 7;         // XCD swizzle: same image -> same XCD L2
    int l  = blockIdx.x >> 3;        // 0..255
    int bl = b * 256 + l;

    if (l == 255) {                  // its top-16 feeds only excluded row 0
        if (threadIdx.x == 0) partial[bl] = 0.0f;
        return;
    }

    // ---- pooled for this query (thread 0) ----
    if (threadIdx.x == 0) {
        int i = l * BS + b;          // scrambled flat grid row
        int b2 = i >> 8, l2 = i & 255;
        const float* pr = pred + ((b2 * 256 + l2) * 8);
        float x = pr[0], y = pr[1];
        float fx = rintf(__fsub_rn(__fmul_rn(x, 192.0f), 0.5f));
        float fy = rintf(__fsub_rn(__fmul_rn(y, 192.0f), 0.5f));
        int ix = (int)fx, iy = (int)fy;
        int inb = (ix >= 0 && ix < WW && iy >= 0 && iy < HH) ? 1 : 0;
        int ixc = min(max(ix, 0), WW - 1);
        int iyc = min(max(iy, 0), HH - 1);
        float m = (float)inb;
        const float* img = ref + b * 3 * HW + iyc * WW + ixc;
        float p0 = __fmul_rn(img[0], m);
        float p1 = __fmul_rn(img[HW], m);
        float p2 = __fmul_rn(img[2 * HW], m);
        float psq = __fadd_rn(__fadd_rn(__fmul_rn(p0, p0), __fmul_rn(p1, p1)), __fmul_rn(p2, p2));
        spool = make_float4(p0, p1, p2, psq);
    }
    __syncthreads();
    float4 pq = spool;

    const float4* p0g = (const float4*)(ref + (size_t)b * 3 * HW);  // +9216/+18432 per plane
    int wq4 = wid * 2304;            // wave's quarter (float4 units)
    u64* qw = qbuf[wid];

    // ---- warm-up: quarter's first 4 sites, exact sims, bitonic ----
    u64 kept[KK];
    #pragma unroll
    for (int it = 0; it < 4; ++it) {
        int v = wq4 + it * 64 + lane;
        float4 a0 = p0g[v], a1 = p0g[v + 9216], a2 = p0g[v + 18432];
        int base = v * 4;
        #define WARM(comp, e)                                                      \
        {                                                                          \
            float rs = exact_rsq(a0.comp, a1.comp, a2.comp);                       \
            float s  = exact_sim(a0.comp, a1.comp, a2.comp, rs, pq);               \
            kept[it * 4 + e] = ((u64)fkey(s) << 32) | (uint32_t)(base + e);        \
        }
        WARM(x, 0) WARM(y, 1) WARM(z, 2) WARM(w, 3)
        #undef WARM
    }
    bitonic16(kept);

    uint32_t tk = refine_tau(kept, 0xFF7FFFFFu, 12);
    float h = __fmul_rn(__fsub_rn(pq.w, __fadd_rn(inv_fkey(tk), PAD)), 0.5f);

    // ---- main scan: sites 4..35, 1-site prefetch, FMA filter ----
    uint32_t scnt = 0;
    int vp = wq4 + 4 * 64 + lane;
    float4 n0 = p0g[vp], n1 = p0g[vp + 9216], n2 = p0g[vp + 18432];

    #pragma unroll 1
    for (int it = 4; it < 36; ++it) {
        float4 a0 = n0, a1 = n1, a2 = n2;
        int itn = (it < 35) ? it + 1 : 35;
        int vn = wq4 + itn * 64 + lane;
        n0 = p0g[vn]; n1 = p0g[vn + 9216]; n2 = p0g[vn + 18432];

        int base = (wq4 + it * 64 + lane) * 4;
        // fast filter: pass <=> cross_fma >= fma(rsq_fma, 0.5, h)  (pad-safe)
        #define FILT(comp, g)                                                          \
            bool g;                                                                    \
            {                                                                          \
                float rsf = fmaf(a2.comp, a2.comp, fmaf(a1.comp, a1.comp,              \
                                 a0.comp * a0.comp));                                  \
                float crf = fmaf(a2.comp, pq.z, fmaf(a1.comp, pq.y, a0.comp * pq.x));  \
                g = crf >= fmaf(rsf, 0.5f, h);                                         \
            }
        FILT(x, g0) FILT(y, g1) FILT(z, g2) FILT(w, g3)
        #undef FILT

        if (__ballot(g0 | g1 | g2 | g3)) {
            #define PUSHQ(pp, e, eidx)                                                     \
            {                                                                              \
                u64 pm = __ballot(pp);                                                     \
                if (pm) {                                                                  \
                    if (pp) {                                                              \
                        float rse = exact_rsq(a0.e, a1.e, a2.e);                           \
                        float sx  = exact_sim(a0.e, a1.e, a2.e, rse, pq);                  \
                        uint32_t rank = __builtin_amdgcn_mbcnt_hi((uint32_t)(pm >> 32),    \
                                         __builtin_amdgcn_mbcnt_lo((uint32_t)pm, 0));      \
                        qw[scnt + rank] = ((u64)fkey(sx) << 32) | (uint32_t)(base + eidx); \
                    }                                                                      \
                    scnt += (uint32_t)__popcll(pm);                                        \
                }                                                                          \
            }
            PUSHQ(g0, x, 0) PUSHQ(g1, y, 1) PUSHQ(g2, z, 2) PUSHQ(g3, w, 3)
            #undef PUSHQ

            if (scnt >= 64u) {
                for (uint32_t e = lane; e < scnt; e += 64) insert64(kept, qw[e]);
                scnt = 0;
                tk = refine_tau(kept, tk, 8);
                h = __fmul_rn(__fsub_rn(pq.w, __fadd_rn(inv_fkey(tk), PAD)), 0.5f);
            }
        }
    }
    for (uint32_t e = lane; e < scnt; e += 64) insert64(kept, qw[e]);

    // ---- per-wave top-16 -> mbuf, then wave 0 merges 64 candidates ----
    int M = stage_compact(kept, tk, cbufs[wid], lane);
    select16(kept, M, cbufs[wid], &mbuf[wid * KK], lane);
    __syncthreads();

    if (wid == 0) {
        u64 v = mbuf[lane];               // 64 distinct keys (distinct pixel idx)
        int rank = 0;
        #pragma unroll 1
        for (int m = 0; m < 64; ++m) {
            uint32_t lo = __shfl((uint32_t)v, m, 64);
            uint32_t hi = __shfl((uint32_t)(v >> 32), m, 64);
            u64 o = ((u64)hi << 32) | lo;
            rank += (o < v) ? 1 : 0;
        }
        // loss term for row l+1: argmin over top-16 targets (tie -> smallest rank)
        float px1 = pred[(size_t)(bl + 1) * 8 + 0];
        float py1 = pred[(size_t)(bl + 1) * 8 + 1];
        float tx = 0.0f, ty = 0.0f;
        u64 dkey = ~0ull;
        if (rank < KK) {
            uint32_t idx = (uint32_t)v;
            tx = (float)(idx % WW) / 192.0f;
            ty = (float)(idx / WW) / 192.0f;
            float dx = __fsub_rn(px1, tx);
            float dy = __fsub_rn(py1, ty);
            float d = __fadd_rn(__fmul_rn(dx, dx), __fmul_rn(dy, dy));
            dkey = ((u64)__float_as_uint(d) << 32) | (uint32_t)rank;  // d>=0: bits monotone
        }
        u64 wmin = wave_min_u64(dkey);
        if (dkey == wmin && rank < KK) {   // exactly one winner (ranks distinct)
            float ex = __fsub_rn(px1, tx);
            float ey = __fsub_rn(py1, ty);
            partial[bl] = __fadd_rn(__fmul_rn(ex, ex), __fmul_rn(ey, ey));
        }
    }
}

// ---------- kernel 2: reduce 2048 partials -> mean ----------
__global__ __launch_bounds__(256) void reduce_kernel(const float* __restrict__ partial,
                                                     float* __restrict__ out) {
    __shared__ double sred[256];
    double a = 0.0;
    #pragma unroll
    for (int i = 0; i < 8; ++i) a += (double)partial[i * 256 + threadIdx.x];
    sred[threadIdx.x] = a;
    __syncthreads();
    for (int s = 128; s > 0; s >>= 1) {
        if (threadIdx.x < s) sred[threadIdx.x] += sred[threadIdx.x + s];
        __syncthreads();
    }
    if (threadIdx.x == 0) out[0] = (float)(sred[0] / 2040.0);
}

// ---------- launch ----------
extern "C" void kernel_launch(void* const* d_in, const int* in_sizes, int n_in,
                              void* d_out, int out_size, void* d_ws, size_t ws_size,
                              hipStream_t stream) {
    const float* pred = (const float*)d_in[0];   // (8,256,8) f32
    const float* ref  = (const float*)d_in[1];   // (8,3,192,192) f32
    float* out = (float*)d_out;

    float* partial = (float*)d_ws;               // 2048 floats, fully overwritten each call

    topk_kernel  <<<2048, 256, 0, stream>>>(pred, ref, partial);
    reduce_kernel<<<1, 256, 0, stream>>>(partial, out);
}